// Round 7
// baseline (199.598 us; speedup 1.0000x reference)
//
#include <hip/hip_runtime.h>
#include <stdint.h>

// Maj3FC: out[b,c] = 2.25 * sum_g sign( sum_{k<3} sign(x[b,3g+k])*sign(w[c,3g+k]) )
// B=512, C_IN=1536, C_OUT=512, G=512 groups of 3. Exact integer math -> absmax 0.
//
// R13: single-launch fusion via full-residency flag barrier.
// Ledger: R7 -3.5 (VALU cut), R8 +1.4, R9 -1.9 (ballot pack), R10 -0.5
// (2x2 reg block), R11 FAIL (hipLaunchCooperativeKernel no-ops under graph
// capture), R12 +6.7 (launch_bounds(256,8) spilled; 1-unit pack waves).
// Model: fill ~41us fixed; pack ~1.5us; maj3 ~3.5us; residual ~18us =
// 2 kernel-node envelopes + gaps. Fix: ONE kernel node.
//  - grid 1024 blocks @ launch_bounds(256,4): VGPR<=128, LDS 16.9KB ->
//    4 blocks/CU x 256 CU = exactly 1024 co-resident (capacity barrier OK).
//  - phase A: block packs row (blockIdx.y*32+blockIdx.x) with R9's ballot
//    pack (wave = 2 chunks). threadfence + release-store flags[row]=MAGIC.
//  - barrier: every wave acquire-polls ONLY the 32 row-flags its tile
//    needs (lanes 0..31). Bounded spin (-> visible fail, never a hang).
//    ws is re-poisoned every iter so flags start as poison; MAGIC collision
//    with a fill pattern ~2^-32.
//  - phase B: R10 maj3 verbatim (16x16 tile, split-K4, 2x2 micro-tile).
//
// Bit-plane format: chunk = 64 groups = 3 uint4 = 12 dwords:
//   P0a P0b P1a P1b | P2a P2b N0a N0b | N1a N1b N2a N2b
// a = ballot lo 32 lanes, b = hi 32; Pk/Nk = sign planes of element k.
// Row = 8 chunks = 96 dwords.

#define CIN     1536
#define B_DIM   512
#define COUT    512
#define GROUPS  512   // CIN/3 exact
#define ROW_U4  24    // uint4 per packed row
#define XSTRIDE 25    // LDS row stride in uint4 (100 dwords)
#define FLAG_MAGIC 0x6D4A3C95u

// 32 groups per call: cp = #(+1 products), cn = #(-1); contribution
// (cp>cn)+(cp>=cn) = sign+1. sum(sign) over 512 groups = acc_total - 512.
__device__ __forceinline__ void maj32(
    unsigned xp0, unsigned xp1, unsigned xp2,
    unsigned xn0, unsigned xn1, unsigned xn2,
    unsigned wp0, unsigned wp1, unsigned wp2,
    unsigned wn0, unsigned wn1, unsigned wn2,
    int& acc) {
  unsigned pos0 = (xp0 & wp0) | (xn0 & wn0);
  unsigned pos1 = (xp1 & wp1) | (xn1 & wn1);
  unsigned pos2 = (xp2 & wp2) | (xn2 & wn2);
  unsigned neg0 = (xp0 & wn0) | (xn0 & wp0);
  unsigned neg1 = (xp1 & wn1) | (xn1 & wp1);
  unsigned neg2 = (xp2 & wn2) | (xn2 & wp2);
  unsigned sa  = pos0 ^ pos1;
  unsigned cp0 = sa ^ pos2;
  unsigned cp1 = (pos0 & pos1) | (pos2 & sa);
  unsigned sb  = neg0 ^ neg1;
  unsigned cn0 = sb ^ neg2;
  unsigned cn1 = (neg0 & neg1) | (neg2 & sb);
  unsigned nh = ~cn1;
  unsigned nl = ~cn0;
  unsigned hi = cp1 & nh;
  unsigned eq = ~(cp1 ^ cn1);
  unsigned gt = hi | (eq & (cp0 & nl));
  unsigned ge = hi | (eq & (cp0 | nl));
  acc += __popc(gt) + __popc(ge);
}

// One chunk (3 uint4 per operand) for one (b,c) pair: both 32-group slices.
__device__ __forceinline__ void chunk_bc(
    const uint4& a0, const uint4& a1, const uint4& a2,
    const uint4& b0, const uint4& b1, const uint4& b2,
    int& acc) {
  maj32(a0.x, a0.z, a1.x, a1.z, a2.x, a2.z,
        b0.x, b0.z, b1.x, b1.z, b2.x, b2.z, acc);
  maj32(a0.y, a0.w, a1.y, a1.w, a2.y, a2.w,
        b0.y, b0.w, b1.y, b1.w, b2.y, b2.w, acc);
}

// grid = (32, 32) = 1024 blocks x 256 threads, exactly 4 blocks/CU resident.
// LDS = 2*16*25*16 + 4*256*4 = 16.9 KB.
__global__ __launch_bounds__(256, 4) void fused_kernel(
    const float* __restrict__ x, const float* __restrict__ w,
    uint32_t* __restrict__ packed, uint32_t* flags,
    float* __restrict__ out) {
  __shared__ __align__(16) uint4 sx[16][XSTRIDE];
  __shared__ __align__(16) uint4 sw[16][XSTRIDE];
  __shared__ int comb[4][256];

  const int tid = threadIdx.x;
  const int lane = tid & 63;
  const int q    = tid >> 6;           // wave id 0..3
  const int b0 = blockIdx.y * 16;
  const int c0 = blockIdx.x * 16;
  const int myrow = blockIdx.y * 32 + blockIdx.x;   // 0..1023, 1:1 with rows

  // ---------------- phase A: ballot-pack row `myrow` ----------------
  {
    const float* src = (myrow < B_DIM) ? (x + (size_t)myrow * CIN)
                                       : (w + (size_t)(myrow - B_DIM) * CIN);
    const int j  = lane >> 1;   // plane word (0..5) this lane stores
    const int hi = lane & 1;    // lo/hi half of the u64
    #pragma unroll
    for (int si = 0; si < 2; si++) {
      const int s = 2 * q + si;                       // chunk 0..7
      const float3 f = ((const float3*)src)[64 * s + lane];
      unsigned long long P0 = __ballot(f.x > 0.0f);
      unsigned long long N0 = __ballot(f.x < 0.0f);
      unsigned long long P1 = __ballot(f.y > 0.0f);
      unsigned long long N1 = __ballot(f.y < 0.0f);
      unsigned long long P2 = __ballot(f.z > 0.0f);
      unsigned long long N2 = __ballot(f.z < 0.0f);
      unsigned h0 = hi ? (unsigned)(P0 >> 32) : (unsigned)P0;
      unsigned h1 = hi ? (unsigned)(P1 >> 32) : (unsigned)P1;
      unsigned h2 = hi ? (unsigned)(P2 >> 32) : (unsigned)P2;
      unsigned h3 = hi ? (unsigned)(N0 >> 32) : (unsigned)N0;
      unsigned h4 = hi ? (unsigned)(N1 >> 32) : (unsigned)N1;
      unsigned h5 = hi ? (unsigned)(N2 >> 32) : (unsigned)N2;
      unsigned v01 = (j == 1) ? h1 : h0;
      unsigned v23 = (j == 3) ? h3 : h2;
      unsigned v45 = (j == 5) ? h5 : h4;
      unsigned val = (j < 2) ? v01 : ((j < 4) ? v23 : v45);
      if (lane < 12) packed[(size_t)myrow * 96 + s * 12 + lane] = val;
    }
  }
  // release: every thread drains/flushes its own stores, then one flag store
  __threadfence();
  __syncthreads();
  if (tid == 0)
    __hip_atomic_store(&flags[myrow], FLAG_MAGIC,
                       __ATOMIC_RELEASE, __HIP_MEMORY_SCOPE_AGENT);

  // ---------------- barrier: wait for the 32 rows this tile consumes ------
  {
    int fidx = (lane < 16) ? (b0 + lane)
                           : (B_DIM + c0 + (lane - 16));  // w rows at 512+
    int tries = 0;
    for (;;) {
      bool ok = true;
      if (lane < 32)
        ok = (__hip_atomic_load(&flags[fidx], __ATOMIC_ACQUIRE,
                                __HIP_MEMORY_SCOPE_AGENT) == FLAG_MAGIC);
      if (__all(ok)) break;
      if (++tries > (1 << 20)) break;   // bounded: fail visibly, never hang
      __builtin_amdgcn_s_sleep(2);
    }
  }

  // ---------------- phase B: maj3 (R10 verbatim) ----------------
  const uint4* px = (const uint4*)packed;                         // rows 0..511
  const uint4* pw = (const uint4*)(packed + (size_t)B_DIM * 96);  // rows 512..1023

  // stage 32 rows x 24 uint4: thread -> row tid>>3, 3 consecutive uint4.
  {
    const int r  = tid >> 3;           // 0..31
    const int wd = (tid & 7) * 3;      // 0..21
    const uint4* g = (r < 16) ? (px + (size_t)(b0 + r) * ROW_U4 + wd)
                              : (pw + (size_t)(c0 + r - 16) * ROW_U4 + wd);
    uint4* d = (r < 16) ? &sx[r][wd] : &sw[r - 16][wd];
    d[0] = g[0]; d[1] = g[1]; d[2] = g[2];
  }
  __syncthreads();

  const int t2c = tid & 7;         // c-pair index
  const int t2b = (tid >> 3) & 7;  // b-pair index
  // q = K-quarter: chunks [2q, 2q+2)

  const uint4* xr0 = &sx[2 * t2b][q * 6];
  const uint4* xr1 = &sx[2 * t2b + 1][q * 6];
  const uint4* wc0 = &sw[2 * t2c][q * 6];
  const uint4* wc1 = &sw[2 * t2c + 1][q * 6];

  int a00 = 0, a01 = 0, a10 = 0, a11 = 0;
  #pragma unroll
  for (int i = 0; i < 2; i++) {    // 2 chunks per quarter
    uint4 xa0 = xr0[3 * i], xa1 = xr0[3 * i + 1], xa2 = xr0[3 * i + 2];
    uint4 xb0 = xr1[3 * i], xb1 = xr1[3 * i + 1], xb2 = xr1[3 * i + 2];
    uint4 wa0 = wc0[3 * i], wa1 = wc0[3 * i + 1], wa2 = wc0[3 * i + 2];
    uint4 wb0 = wc1[3 * i], wb1 = wc1[3 * i + 1], wb2 = wc1[3 * i + 2];
    chunk_bc(xa0, xa1, xa2, wa0, wa1, wa2, a00);
    chunk_bc(xa0, xa1, xa2, wb0, wb1, wb2, a01);
    chunk_bc(xb0, xb1, xb2, wa0, wa1, wa2, a10);
    chunk_bc(xb0, xb1, xb2, wb0, wb1, wb2, a11);
  }

  const int ob = 2 * t2b, oc = 2 * t2c;
  comb[q][ob * 16 + oc]           = a00;
  comb[q][ob * 16 + oc + 1]       = a01;
  comb[q][(ob + 1) * 16 + oc]     = a10;
  comb[q][(ob + 1) * 16 + oc + 1] = a11;
  __syncthreads();

  const int o = tid;
  int total = comb[0][o] + comb[1][o] + comb[2][o] + comb[3][o];
  // total = sum over 512 groups of (sign+1) -> sum(sign) = total - 512
  out[(size_t)(b0 + (o >> 4)) * COUT + c0 + (o & 15)] =
      2.25f * (float)(total - GROUPS);
}

extern "C" void kernel_launch(void* const* d_in, const int* in_sizes, int n_in,
                              void* d_out, int out_size, void* d_ws, size_t ws_size,
                              hipStream_t stream) {
  const float* x = (const float*)d_in[0];   // [512, 1536]
  const float* w = (const float*)d_in[1];   // [512, 1536]
  float* out = (float*)d_out;               // [512, 512]

  uint32_t* packed = (uint32_t*)d_ws;                     // [1024][96] = 384 KB
  uint32_t* flags  = packed + (size_t)1024 * 96;          // [1024] dwords = 4 KB

  dim3 grid(32, 32);
  fused_kernel<<<grid, 256, 0, stream>>>(x, w, packed, flags, out);
}

// Round 8
// 63.793 us; speedup vs baseline: 3.1288x; 3.1288x over previous
//
#include <hip/hip_runtime.h>
#include <stdint.h>

// Maj3FC: out[b,c] = 2.25 * sum_g sign( sum_{k<3} sign(x[b,3g+k])*sign(w[c,3g+k]) )
// B=512, C_IN=1536, C_OUT=512, G=512 groups of 3. Exact integer math -> absmax 0.
//
// R14: revert to R10 verbatim (best measured: 64.17us, passed).
// Final ledger: R7 -3.5 (bit-plane VALU cut), R8 +1.4 (wave-uniform x,
// occupancy loss), R9 -1.9 (ballot pack), R10 -0.5 (2x2 reg blocking),
// R11 FAIL (hipLaunchCooperativeKernel no-ops under graph capture),
// R12 +6.7 (launch_bounds(256,8) spill + 1-unit pack), R13 +135 (flag-spin
// fusion: agent-scope polling throttles producers; kernel 145us, VALUBusy
// 2.7%).
// Budget model (calibrated by R13's one-node iteration): fill ~41us
// (harness ws poison, 256MiB @ 82% HBM peak) + ~14us fixed graph/host
// envelope + pack ~2 + maj3 ~4.5 + ~2 node gap. Harness floor ~55us;
// remaining kernel-side upside <= 2us with all structural levers measured
// negative. This is the stopping point.
//
// Bit-plane format: chunk = 64 groups = 3 uint4 = 12 dwords:
//   P0a P0b P1a P1b | P2a P2b N0a N0b | N1a N1b N2a N2b
// a = ballot lo 32 lanes, b = hi 32; Pk/Nk = sign planes of element k.
// Row = 8 chunks = 96 dwords.

#define CIN     1536
#define B_DIM   512
#define COUT    512
#define GROUPS  512   // CIN/3 exact
#define ROW_U4  24    // uint4 per packed row
#define XSTRIDE 25    // LDS row stride in uint4 (100 dwords)

// ---------------- pack kernel (R9, measured win) ----------------
// 512 blocks x 256 threads = 2048 waves. Wave gw -> (row = gw>>1, half = gw&1),
// handles chunks [4*half, 4*half+4). Lane = group within chunk.
__global__ __launch_bounds__(256) void pack_kernel(
    const float* __restrict__ x, const float* __restrict__ w,
    uint32_t* __restrict__ packed) {
  const int gw   = blockIdx.x * 4 + (threadIdx.x >> 6);  // 0..2047
  const int lane = threadIdx.x & 63;
  const int row  = gw >> 1;
  const int half = gw & 1;
  const float* src = (row < B_DIM) ? (x + (size_t)row * CIN)
                                   : (w + (size_t)(row - B_DIM) * CIN);
  const int j = lane >> 1;          // which plane word (0..5) this lane stores
  const int hi = lane & 1;          // lo/hi half of the u64

  #pragma unroll
  for (int si = 0; si < 4; si++) {
    const int s = 4 * half + si;    // chunk index 0..7
    const float3 f = ((const float3*)src)[64 * s + lane];
    unsigned long long P0 = __ballot(f.x > 0.0f);
    unsigned long long N0 = __ballot(f.x < 0.0f);
    unsigned long long P1 = __ballot(f.y > 0.0f);
    unsigned long long N1 = __ballot(f.y < 0.0f);
    unsigned long long P2 = __ballot(f.z > 0.0f);
    unsigned long long N2 = __ballot(f.z < 0.0f);
    unsigned h0 = hi ? (unsigned)(P0 >> 32) : (unsigned)P0;
    unsigned h1 = hi ? (unsigned)(P1 >> 32) : (unsigned)P1;
    unsigned h2 = hi ? (unsigned)(P2 >> 32) : (unsigned)P2;
    unsigned h3 = hi ? (unsigned)(N0 >> 32) : (unsigned)N0;
    unsigned h4 = hi ? (unsigned)(N1 >> 32) : (unsigned)N1;
    unsigned h5 = hi ? (unsigned)(N2 >> 32) : (unsigned)N2;
    unsigned v01 = (j == 1) ? h1 : h0;
    unsigned v23 = (j == 3) ? h3 : h2;
    unsigned v45 = (j == 5) ? h5 : h4;
    unsigned val = (j < 2) ? v01 : ((j < 4) ? v23 : v45);
    if (lane < 12) packed[(size_t)row * 96 + s * 12 + lane] = val;
  }
}

// ---------------- main kernel ----------------
// 32 groups per call: cp = #(+1 products), cn = #(-1); contribution
// (cp>cn)+(cp>=cn) = sign+1. sum(sign) over 512 groups = acc_total - 512.
__device__ __forceinline__ void maj32(
    unsigned xp0, unsigned xp1, unsigned xp2,
    unsigned xn0, unsigned xn1, unsigned xn2,
    unsigned wp0, unsigned wp1, unsigned wp2,
    unsigned wn0, unsigned wn1, unsigned wn2,
    int& acc) {
  unsigned pos0 = (xp0 & wp0) | (xn0 & wn0);
  unsigned pos1 = (xp1 & wp1) | (xn1 & wn1);
  unsigned pos2 = (xp2 & wp2) | (xn2 & wn2);
  unsigned neg0 = (xp0 & wn0) | (xn0 & wp0);
  unsigned neg1 = (xp1 & wn1) | (xn1 & wp1);
  unsigned neg2 = (xp2 & wn2) | (xn2 & wp2);
  unsigned sa  = pos0 ^ pos1;
  unsigned cp0 = sa ^ pos2;
  unsigned cp1 = (pos0 & pos1) | (pos2 & sa);
  unsigned sb  = neg0 ^ neg1;
  unsigned cn0 = sb ^ neg2;
  unsigned cn1 = (neg0 & neg1) | (neg2 & sb);
  unsigned nh = ~cn1;
  unsigned nl = ~cn0;
  unsigned hi = cp1 & nh;
  unsigned eq = ~(cp1 ^ cn1);
  unsigned gt = hi | (eq & (cp0 & nl));
  unsigned ge = hi | (eq & (cp0 | nl));
  acc += __popc(gt) + __popc(ge);
}

// One chunk (3 uint4 per operand) for one (b,c) pair: both 32-group slices.
__device__ __forceinline__ void chunk_bc(
    const uint4& a0, const uint4& a1, const uint4& a2,
    const uint4& b0, const uint4& b1, const uint4& b2,
    int& acc) {
  maj32(a0.x, a0.z, a1.x, a1.z, a2.x, a2.z,
        b0.x, b0.z, b1.x, b1.z, b2.x, b2.z, acc);
  maj32(a0.y, a0.w, a1.y, a1.w, a2.y, a2.w,
        b0.y, b0.w, b1.y, b1.w, b2.y, b2.w, acc);
}

// 16(b) x 16(c) tile, 256 threads, split-K 4 (wave = quarter = 2 chunks),
// thread = 2b x 2c micro-tile. grid = (32, 32) = 1024 blocks -> 4 blocks/CU
// -> 16 waves/CU. LDS = 2*16*25*16 + 4*256*4 = 16.9 KB.
__global__ __launch_bounds__(256, 4) void maj3_kernel(
    const uint4* __restrict__ px, const uint4* __restrict__ pw,
    float* __restrict__ out) {
  __shared__ __align__(16) uint4 sx[16][XSTRIDE];
  __shared__ __align__(16) uint4 sw[16][XSTRIDE];
  __shared__ int comb[4][256];

  const int b0 = blockIdx.y * 16;
  const int c0 = blockIdx.x * 16;
  const int tid = threadIdx.x;

  // stage 32 rows x 24 uint4: thread -> row tid>>3, 3 consecutive uint4 at
  // (tid&7)*3. 384B contiguous per row, rows dense in global -> coalesced.
  {
    const int r  = tid >> 3;           // 0..31
    const int wd = (tid & 7) * 3;      // 0..21
    const uint4* g = (r < 16) ? (px + (size_t)(b0 + r) * ROW_U4 + wd)
                              : (pw + (size_t)(c0 + r - 16) * ROW_U4 + wd);
    uint4* d = (r < 16) ? &sx[r][wd] : &sw[r - 16][wd];
    d[0] = g[0]; d[1] = g[1]; d[2] = g[2];
  }
  __syncthreads();

  const int t2c = tid & 7;         // c-pair index
  const int t2b = (tid >> 3) & 7;  // b-pair index
  const int q   = tid >> 6;        // K-quarter (= wave id): chunks [2q, 2q+2)

  const uint4* xr0 = &sx[2 * t2b][q * 6];
  const uint4* xr1 = &sx[2 * t2b + 1][q * 6];
  const uint4* wc0 = &sw[2 * t2c][q * 6];
  const uint4* wc1 = &sw[2 * t2c + 1][q * 6];

  int a00 = 0, a01 = 0, a10 = 0, a11 = 0;
  #pragma unroll
  for (int i = 0; i < 2; i++) {    // 2 chunks per quarter
    uint4 xa0 = xr0[3 * i], xa1 = xr0[3 * i + 1], xa2 = xr0[3 * i + 2];
    uint4 xb0 = xr1[3 * i], xb1 = xr1[3 * i + 1], xb2 = xr1[3 * i + 2];
    uint4 wa0 = wc0[3 * i], wa1 = wc0[3 * i + 1], wa2 = wc0[3 * i + 2];
    uint4 wb0 = wc1[3 * i], wb1 = wc1[3 * i + 1], wb2 = wc1[3 * i + 2];
    chunk_bc(xa0, xa1, xa2, wa0, wa1, wa2, a00);
    chunk_bc(xa0, xa1, xa2, wb0, wb1, wb2, a01);
    chunk_bc(xb0, xb1, xb2, wa0, wa1, wa2, a10);
    chunk_bc(xb0, xb1, xb2, wb0, wb1, wb2, a11);
  }

  // per-quarter partials (o = row-in-tile * 16 + col-in-tile)
  const int ob = 2 * t2b, oc = 2 * t2c;
  comb[q][ob * 16 + oc]           = a00;
  comb[q][ob * 16 + oc + 1]       = a01;
  comb[q][(ob + 1) * 16 + oc]     = a10;
  comb[q][(ob + 1) * 16 + oc + 1] = a11;
  __syncthreads();

  // combine: thread tid owns output tid; comb[q][tid] reads are 2-way (free)
  const int o = tid;
  int total = comb[0][o] + comb[1][o] + comb[2][o] + comb[3][o];
  // total = sum over 512 groups of (sign+1) -> sum(sign) = total - 512
  out[(size_t)(b0 + (o >> 4)) * COUT + c0 + (o & 15)] =
      2.25f * (float)(total - GROUPS);
}

extern "C" void kernel_launch(void* const* d_in, const int* in_sizes, int n_in,
                              void* d_out, int out_size, void* d_ws, size_t ws_size,
                              hipStream_t stream) {
  const float* x = (const float*)d_in[0];   // [512, 1536]
  const float* w = (const float*)d_in[1];   // [512, 1536]
  float* out = (float*)d_out;               // [512, 512]

  uint32_t* packed = (uint32_t*)d_ws;       // [1024][96] dwords = 384 KB
  const uint4* px = (const uint4*)packed;                        // rows 0..511 (x)
  const uint4* pw = (const uint4*)(packed + (size_t)B_DIM * 96); // rows 512..1023 (w)

  pack_kernel<<<512, 256, 0, stream>>>(x, w, packed);

  dim3 grid(COUT / 16, B_DIM / 16);
  maj3_kernel<<<grid, 256, 0, stream>>>(px, pw, out);
}